// Round 3
// baseline (2191.520 us; speedup 1.0000x reference)
//
#include <hip/hip_runtime.h>
#include <cmath>

typedef unsigned short u16;
typedef unsigned int u32;
typedef float f32x4 __attribute__((ext_vector_type(4)));
typedef short s16x8 __attribute__((ext_vector_type(8)));
typedef u32 u32x4 __attribute__((ext_vector_type(4)));

#define D_MODEL 2048
#define HIDDEN  5461
#define HPAD    5504      // 43*128
#define WCNT    11184128  // HIDDEN*D_MODEL

// ---- bf16 round-to-nearest-even ----
__device__ __forceinline__ u16 f2bf(float f) {
  union { float f; u32 u; } c; c.f = f;
  u32 u = c.u + 0x7fffu + ((c.u >> 16) & 1u);
  return (u16)(u >> 16);
}

// ---- async global->LDS, 16B per lane ----
__device__ __forceinline__ void async16(const void* g, void* l) {
  __builtin_amdgcn_global_load_lds(
      (const __attribute__((address_space(1))) unsigned int*)g,
      (__attribute__((address_space(3))) unsigned int*)l, 16, 0, 0);
}

__global__ void zero_sums_kernel(double* __restrict__ s) {
  if (threadIdx.x < 3) s[threadIdx.x] = 0.0;
}

// ---- |w| sum reduction in f64 (decision-boundary-grade precision) ----
__global__ void abssum_kernel(const float* __restrict__ w, long n, double* __restrict__ out) {
  long i0 = ((long)blockIdx.x * blockDim.x + threadIdx.x) * 4;
  long stride = (long)gridDim.x * blockDim.x * 4;
  double s = 0.0;
  for (long i = i0; i < n; i += stride) {
    float4 v = *(const float4*)(w + i);
    s += (double)fabsf(v.x) + (double)fabsf(v.y) + (double)fabsf(v.z) + (double)fabsf(v.w);
  }
#pragma unroll
  for (int off = 32; off > 0; off >>= 1) s += __shfl_down(s, off, 64);
  __shared__ double ls[4];
  int lane = threadIdx.x & 63, wv = threadIdx.x >> 6;
  if (lane == 0) ls[wv] = s;
  __syncthreads();
  if (threadIdx.x == 0) atomicAdd(out, ls[0] + ls[1] + ls[2] + ls[3]);
}

// ---- quantize w1/w3 [HIDDEN, 2048] -> ternary bf16 staged [nt 0..42][kg 0..255][128][8] ----
__global__ void quant13_kernel(const float* __restrict__ w, const double* __restrict__ sum,
                               u16* __restrict__ ws) {
  double s = *sum * (1.0 / (double)WCNT);
  int nt = blockIdx.x;          // 0..42
  int kc = blockIdx.y;          // 0..31
  int nn = threadIdx.x & 127;
  int kl = threadIdx.x >> 7;
  int n = nt * 128 + nn;
  long base = (long)nt * 262144;
#pragma unroll
  for (int it = 0; it < 4; ++it) {
    int kgl = kl + it * 2;
    int kg = kc * 8 + kgl;
    s16x8 qv;
    if (n < HIDDEN) {
      const float* row = w + (long)n * D_MODEL + kc * 64 + kgl * 8;
      float4 a = *(const float4*)(row);
      float4 b = *(const float4*)(row + 4);
      float v[8] = {a.x, a.y, a.z, a.w, b.x, b.y, b.z, b.w};
#pragma unroll
      for (int j = 0; j < 8; ++j) {
        double q = fmin(fmax(rint((double)v[j] / s), -1.0), 1.0);
        qv[j] = (short)f2bf((float)q);
      }
    } else {
#pragma unroll
      for (int j = 0; j < 8; ++j) qv[j] = 0;
    }
    *(s16x8*)(ws + base + ((long)kg * 128 + nn) * 8) = qv;
  }
}

// ---- quantize w2 [2048, HIDDEN] -> staged [nt 0..15][kg 0..687][128][8], k>=HIDDEN -> 0 ----
__global__ void quant2_kernel(const float* __restrict__ w, const double* __restrict__ sum,
                              u16* __restrict__ ws) {
  double s = *sum * (1.0 / (double)WCNT);
  int nt = blockIdx.x;          // 0..15
  int kc = blockIdx.y;          // 0..85
  int nn = threadIdx.x & 127;
  int kl = threadIdx.x >> 7;
  int n = nt * 128 + nn;
  long base = (long)nt * 704512;
#pragma unroll
  for (int it = 0; it < 4; ++it) {
    int kgl = kl + it * 2;
    int kg = kc * 8 + kgl;
    s16x8 qv;
#pragma unroll
    for (int j = 0; j < 8; ++j) {
      int k = kg * 8 + j;
      float q = 0.f;
      if (k < HIDDEN) {
        float v = w[(long)n * HIDDEN + k];
        q = (float)fmin(fmax(rint((double)v / s), -1.0), 1.0);
      }
      qv[j] = (short)f2bf(q);
    }
    *(s16x8*)(ws + base + ((long)kg * 128 + nn) * 8) = qv;
  }
}

// ---- GEMM1 fused: x fp32 (hi/lo split on the fly) x {w1q,w3q} -> g = silu(h1)*h3 -> gs bf16 ----
__global__ __launch_bounds__(256, 2)
void gemm1_kernel(const float* __restrict__ x, const u16* __restrict__ w1s,
                  const u16* __restrict__ w3s, const double* __restrict__ sums,
                  u16* __restrict__ gs) {
  __shared__ alignas(16) u16 Ahi[8192];   // [kg 0..7][128][8]
  __shared__ alignas(16) u16 Alo[8192];
  __shared__ alignas(16) u16 B1s[8192];
  __shared__ alignas(16) u16 B3s[8192];
  const int mt = blockIdx.x, nt = blockIdx.y;
  const int t = threadIdx.x;
  const int lane = t & 63, wave = t >> 6;
  const int wm = wave >> 1, wn = wave & 1;
  const int quad = lane >> 4;
  const int rowA = wm * 64 + (lane & 15);
  const int rowB = wn * 64 + (lane & 15);
  const int arow = t >> 3;    // 0..31
  const int akg  = t & 7;     // 0..7

  f32x4 acc1[4][4], acc3[4][4];
#pragma unroll
  for (int i = 0; i < 4; ++i)
#pragma unroll
    for (int j = 0; j < 4; ++j) {
      acc1[i][j] = {0.f, 0.f, 0.f, 0.f};
      acc3[i][j] = {0.f, 0.f, 0.f, 0.f};
    }

  const float* xb = x + (long)mt * 128 * D_MODEL;
  const u16* B1b = w1s + (long)nt * 262144 + t * 8;
  const u16* B3b = w3s + (long)nt * 262144 + t * 8;

  for (int c = 0; c < 32; ++c) {
    // B: async global->LDS (one 64-k chunk of each weight tile)
    const u16* b1g = B1b + c * 8192;
    const u16* b3g = B3b + c * 8192;
#pragma unroll
    for (int j = 0; j < 4; ++j) {
      async16(b1g + j * 2048, &B1s[t * 8 + j * 2048]);
      async16(b3g + j * 2048, &B3s[t * 8 + j * 2048]);
    }
    // A: load x fp32, split into truncated-hi + truncated-lo bf16, write b128
    const float* xc = xb + c * 64;
#pragma unroll
    for (int p = 0; p < 4; ++p) {
      int row = p * 32 + arow;
      const float* src = xc + (long)row * D_MODEL + akg * 8;
      float4 va = *(const float4*)src;
      float4 vb = *(const float4*)(src + 4);
      float v[8] = {va.x, va.y, va.z, va.w, vb.x, vb.y, vb.z, vb.w};
      u32 hb[8], lb[8];
#pragma unroll
      for (int e = 0; e < 8; ++e) {
        union { float f; u32 u; } cc; cc.f = v[e];
        hb[e] = cc.u & 0xFFFF0000u;
        union { float f; u32 u; } hh; hh.u = hb[e];
        union { float f; u32 u; } dd;
        dd.f = v[e] - hh.f;
        lb[e] = dd.u;
      }
      u32x4 hv, lv;
#pragma unroll
      for (int e = 0; e < 4; ++e) {
        hv[e] = (hb[2 * e] >> 16) | hb[2 * e + 1];
        lv[e] = (lb[2 * e] >> 16) | (lb[2 * e + 1] & 0xFFFF0000u);
      }
      *(u32x4*)&Ahi[akg * 1024 + row * 8] = hv;
      *(u32x4*)&Alo[akg * 1024 + row * 8] = lv;
    }
    __syncthreads();
#pragma unroll
    for (int ks = 0; ks < 2; ++ks) {
      const int kg = ks * 4 + quad;
      s16x8 af[4], b1f[4], b3f[4];
#pragma unroll
      for (int j = 0; j < 4; ++j) {
        b1f[j] = *(const s16x8*)&B1s[kg * 1024 + (rowB + j * 16) * 8];
        b3f[j] = *(const s16x8*)&B3s[kg * 1024 + (rowB + j * 16) * 8];
      }
#pragma unroll
      for (int i = 0; i < 4; ++i)
        af[i] = *(const s16x8*)&Ahi[kg * 1024 + (rowA + i * 16) * 8];
#pragma unroll
      for (int i = 0; i < 4; ++i)
#pragma unroll
        for (int j = 0; j < 4; ++j) {
          acc1[i][j] = __builtin_amdgcn_mfma_f32_16x16x32_bf16(af[i], b1f[j], acc1[i][j], 0, 0, 0);
          acc3[i][j] = __builtin_amdgcn_mfma_f32_16x16x32_bf16(af[i], b3f[j], acc3[i][j], 0, 0, 0);
        }
#pragma unroll
      for (int i = 0; i < 4; ++i)
        af[i] = *(const s16x8*)&Alo[kg * 1024 + (rowA + i * 16) * 8];
#pragma unroll
      for (int i = 0; i < 4; ++i)
#pragma unroll
        for (int j = 0; j < 4; ++j) {
          acc1[i][j] = __builtin_amdgcn_mfma_f32_16x16x32_bf16(af[i], b1f[j], acc1[i][j], 0, 0, 0);
          acc3[i][j] = __builtin_amdgcn_mfma_f32_16x16x32_bf16(af[i], b3f[j], acc3[i][j], 0, 0, 0);
        }
    }
    __syncthreads();
  }

  const float s1 = (float)(sums[0] * (1.0 / (double)WCNT));
  const float s3 = (float)(sums[1] * (1.0 / (double)WCNT));
  u16* gb = gs + (long)mt * 704512;
#pragma unroll
  for (int i = 0; i < 4; ++i) {
    const int r0 = wm * 64 + i * 16 + quad * 4;
#pragma unroll
    for (int j = 0; j < 4; ++j) {
      const int h = nt * 128 + wn * 64 + j * 16 + (lane & 15);
      const int kg2 = h >> 3, jj = h & 7;
#pragma unroll
      for (int rr = 0; rr < 4; ++rr) {
        const int mm = r0 + rr;
        float h1 = acc1[i][j][rr] * s1;
        float h3 = acc3[i][j][rr] * s3;
        float g = (h1 / (1.0f + expf(-h1))) * h3;
        gb[((long)kg2 * 128 + mm) * 8 + jj] = f2bf(g);
      }
    }
  }
}

// ---- GEMM2: out = s2 * (g_bf16 . w2q^T), K = 5504 ----
__global__ __launch_bounds__(256, 2)
void gemm2_kernel(const u16* __restrict__ gs, const u16* __restrict__ w2s,
                  const double* __restrict__ sums, float* __restrict__ out) {
  __shared__ alignas(16) u16 As[8192];
  __shared__ alignas(16) u16 Bs[8192];
  const int mt = blockIdx.x, nt = blockIdx.y;
  const int t = threadIdx.x;
  const int lane = t & 63, wave = t >> 6;
  const int wm = wave >> 1, wn = wave & 1;
  const int quad = lane >> 4;
  const int rowA = wm * 64 + (lane & 15);
  const int rowB = wn * 64 + (lane & 15);

  f32x4 acc[4][4];
#pragma unroll
  for (int i = 0; i < 4; ++i)
#pragma unroll
    for (int j = 0; j < 4; ++j) acc[i][j] = {0.f, 0.f, 0.f, 0.f};

  const u16* Ab = gs  + (long)mt * 704512 + t * 8;
  const u16* Bb = w2s + (long)nt * 704512 + t * 8;

  for (int c = 0; c < 86; ++c) {
    const u16* ag = Ab + (long)c * 8192;
    const u16* bg = Bb + (long)c * 8192;
#pragma unroll
    for (int j = 0; j < 4; ++j) {
      async16(ag + j * 2048, &As[t * 8 + j * 2048]);
      async16(bg + j * 2048, &Bs[t * 8 + j * 2048]);
    }
    __syncthreads();
#pragma unroll
    for (int ks = 0; ks < 2; ++ks) {
      const int kg = ks * 4 + quad;
      s16x8 af[4], bf[4];
#pragma unroll
      for (int i = 0; i < 4; ++i)
        af[i] = *(const s16x8*)&As[kg * 1024 + (rowA + i * 16) * 8];
#pragma unroll
      for (int j = 0; j < 4; ++j)
        bf[j] = *(const s16x8*)&Bs[kg * 1024 + (rowB + j * 16) * 8];
#pragma unroll
      for (int i = 0; i < 4; ++i)
#pragma unroll
        for (int j = 0; j < 4; ++j)
          acc[i][j] = __builtin_amdgcn_mfma_f32_16x16x32_bf16(af[i], bf[j], acc[i][j], 0, 0, 0);
    }
    __syncthreads();
  }

  const float s2 = (float)(sums[2] * (1.0 / (double)WCNT));
#pragma unroll
  for (int i = 0; i < 4; ++i) {
    const int r0 = wm * 64 + i * 16 + quad * 4;
#pragma unroll
    for (int j = 0; j < 4; ++j) {
      const int d = nt * 128 + wn * 64 + j * 16 + (lane & 15);
#pragma unroll
      for (int rr = 0; rr < 4; ++rr) {
        const long m = (long)mt * 128 + r0 + rr;
        out[m * D_MODEL + d] = acc[i][j][rr] * s2;
      }
    }
  }
}

extern "C" void kernel_launch(void* const* d_in, const int* in_sizes, int n_in,
                              void* d_out, int out_size, void* d_ws, size_t ws_size,
                              hipStream_t stream) {
  (void)in_sizes; (void)n_in; (void)out_size; (void)ws_size;
  const float* x  = (const float*)d_in[0];
  const float* w1 = (const float*)d_in[1];
  const float* w3 = (const float*)d_in[2];
  const float* w2 = (const float*)d_in[3];
  float* out = (float*)d_out;

  // workspace layout (total ~236.5 MiB):
  //   sums: 3 f64 (256 B slot)
  //   w1s/w3s: [43][256][128][8] u16 = 11,272,192 elems each (21.5 MiB)
  //   w2s:     [16][688][128][8] u16 = 11,272,192 elems       (21.5 MiB)
  //   gs:      [128][688][128][8] u16 = 90,177,536 elems      (172 MiB)
  char* ws = (char*)d_ws;
  double* sums = (double*)ws;
  u16* w1s = (u16*)(ws + 256);
  u16* w3s = w1s + 11272192L;
  u16* w2s = w3s + 11272192L;
  u16* gs  = w2s + 11272192L;

  zero_sums_kernel<<<1, 64, 0, stream>>>(sums);
  abssum_kernel<<<1024, 256, 0, stream>>>(w1, (long)WCNT, sums + 0);
  abssum_kernel<<<1024, 256, 0, stream>>>(w3, (long)WCNT, sums + 1);
  abssum_kernel<<<1024, 256, 0, stream>>>(w2, (long)WCNT, sums + 2);

  quant13_kernel<<<dim3(43, 32), 256, 0, stream>>>(w1, sums + 0, w1s);
  quant13_kernel<<<dim3(43, 32), 256, 0, stream>>>(w3, sums + 1, w3s);
  quant2_kernel<<<dim3(16, 86), 256, 0, stream>>>(w2, sums + 2, w2s);

  gemm1_kernel<<<dim3(128, 43), 256, 0, stream>>>(x, w1s, w3s, sums, gs);
  gemm2_kernel<<<dim3(128, 16), 256, 0, stream>>>(gs, w2s, sums, out);
}